// Round 4
// baseline (303.554 us; speedup 1.0000x reference)
//
#include <hip/hip_runtime.h>

#define BB 16
#define TT 2000
#define FF 481
#define NDF_ 96
#define ORDER_ 5
#define ROW_F 962          // floats per (b,t) row of spec/out
#define COEF_ROW_F 960     // floats per (b,t) row of coefs

typedef float floatx4 __attribute__((ext_vector_type(4)));

// ---------------------------------------------------------------------------
// Kernel 1: flat float4 streaming copy of spec -> out (entire array).
// 4 independent loads batched before 4 stores -> 4 outstanding 1KB wave-loads.
// Plain loads (let L2/L3 cache spec for the df kernel), nontemporal stores
// (out is write-once here).
// ---------------------------------------------------------------------------
__global__ __launch_bounds__(256) void copy_kernel(
    const floatx4* __restrict__ src, floatx4* __restrict__ dst, int n4)
{
    const int S = gridDim.x * 256;               // stride in float4
    int i = blockIdx.x * 256 + threadIdx.x;

    const int i0 = i, i1 = i + S, i2 = i + 2 * S, i3 = i + 3 * S;
    floatx4 v0, v1, v2, v3;
    bool b0 = i0 < n4, b1 = i1 < n4, b2 = i2 < n4, b3 = i3 < n4;
    if (b0) v0 = src[i0];
    if (b1) v1 = src[i1];
    if (b2) v2 = src[i2];
    if (b3) v3 = src[i3];
    if (b0) __builtin_nontemporal_store(v0, &dst[i0]);
    if (b1) __builtin_nontemporal_store(v1, &dst[i1]);
    if (b2) __builtin_nontemporal_store(v2, &dst[i2]);
    if (b3) __builtin_nontemporal_store(v3, &dst[i3]);
}

// ---------------------------------------------------------------------------
// Kernel 2: 5-tap complex FIR + alpha blend on bins [0,96).
// Block = 768 threads = 8 t-rows x 96 bins. The 12 needed spec rows
// (8 + 4 halo, 192 floats each) are staged in LDS once; all taps AND the
// blend input (tap k=4) read from LDS. float2 LDS reads across 96
// consecutive lanes = 2-way bank alias = free.
// ---------------------------------------------------------------------------
#define ROWS_PER_BLK 8
#define LDS_ROWS (ROWS_PER_BLK + ORDER_ - 1)   // 12
#define LDS_F2_PER_ROW NDF_                    // 96 float2 per row
#define LDS_F2_TOTAL (LDS_ROWS * LDS_F2_PER_ROW) // 1152

__global__ __launch_bounds__(768) void df_kernel(
    const float* __restrict__ spec,
    const float* __restrict__ coefs,
    const float* __restrict__ alpha,
    float* __restrict__ out)
{
    __shared__ float2 xs[LDS_F2_TOTAL];

    const int b  = blockIdx.x / (TT / ROWS_PER_BLK);
    const int t0 = (blockIdx.x - b * (TT / ROWS_PER_BLK)) * ROWS_PER_BLK;
    const int tid = threadIdx.x;

    // Cooperative LDS fill: 1152 float2 by 768 threads (1.5 per thread).
    for (int j = tid; j < LDS_F2_TOTAL; j += 768) {
        const int jr  = j / LDS_F2_PER_ROW;        // LDS row [0,12)
        const int jc  = j - jr * LDS_F2_PER_ROW;   // float2 col [0,96)
        const int t   = t0 - (ORDER_ - 1) + jr;
        float2 v = make_float2(0.0f, 0.0f);
        if (t >= 0) {
            v = *(const float2*)(spec + ((long)b * TT + t) * ROW_F + jc * 2);
        }
        xs[j] = v;
    }
    __syncthreads();

    const int r  = tid / NDF_;        // row within chunk [0,8)
    const int f  = tid - r * NDF_;    // DF bin [0,96)
    const int t  = t0 + r;
    const int bt = b * TT + t;

    const float a   = alpha[bt];
    const float oma = 1.0f - a;

    float acc_re = 0.0f, acc_im = 0.0f;
    const float2* cbase = (const float2*)(coefs + (long)bt * COEF_ROW_F + f * 2);
    #pragma unroll
    for (int k = 0; k < ORDER_; ++k) {
        const float2 x = xs[(r + k) * LDS_F2_PER_ROW + f];
        const float2 c = cbase[k * NDF_];
        acc_re += x.x * c.x - x.y * c.y;
        acc_im += x.y * c.x + x.x * c.y;
    }

    // Blend input = tap k=ORDER-1 (the t row itself), already in LDS.
    const float2 s = xs[(r + ORDER_ - 1) * LDS_F2_PER_ROW + f];
    float2 o;
    o.x = acc_re * a + s.x * oma;
    o.y = acc_im * a + s.y * oma;
    *(float2*)(out + (long)bt * ROW_F + f * 2) = o;
}

extern "C" void kernel_launch(void* const* d_in, const int* in_sizes, int n_in,
                              void* d_out, int out_size, void* d_ws, size_t ws_size,
                              hipStream_t stream) {
    const float* spec  = (const float*)d_in[0];
    const float* coefs = (const float*)d_in[1];
    const float* alpha = (const float*)d_in[2];
    float* out = (float*)d_out;

    const int n4 = (BB * TT * FF * 2) / 4;   // 7,696,000 float4
    // 4 float4 per thread: ceil(7,696,000 / (256*4)) = 7516 blocks
    copy_kernel<<<7516, 256, 0, stream>>>((const floatx4*)spec, (floatx4*)out, n4);

    df_kernel<<<BB * (TT / ROWS_PER_BLK), 768, 0, stream>>>(spec, coefs, alpha, out);
}